// Round 8
// baseline (6028.629 us; speedup 1.0000x reference)
//
#include <hip/hip_runtime.h>
#include <math.h>

#define N_NODES 25000
#define N_EDGES 800000
#define IN_SZ 64
#define S_DIM 128
#define V_DIM 16
#define H_DIM 17
#define GVP_EPS 1e-8f
#define LN_EPS 1e-5f
#define INV_Z 0.1f
#define TE 64  // edges per block in edge_gemm

// ---- LDS layout for edge_gemm (float offsets) ----
// A region (0..3839): VE_t [64][3][20]  (P1a-P1b)
//   overlays: WSC (0..2243, P2), SH2 (2560..3647, P1c..P2-kc8), WgT (0..2047, gate)
// B region (3840..7679): VH_t [64][3][20] (P1b-P1d)
// ZL (7680..8959): [64][20] z chunks (P2)
// VU (8960..12031): [64][48] (P1d..P4; VM in-place at P3b)
// weights/idx: WHL 289, WUL 272, ST 64, DT 64
// SM overlay (P3c-P4): 0..8447, stride 132, XOR-swizzled
#define A_O 0
#define WSC_O 0
#define WSTR 132
#define SH2_O 2560
#define B_O 3840
#define ZL_O 7680
#define VU_O 8960
#define WHL_O 12032
#define WUL_O 12321
#define ST_O 12593
#define DT_O 12657
#define LDS_F 12721
#define SM_O 0
#define SMSTR 132
#define WGT_O 0

__device__ __forceinline__ float wave_sum(float x) {
#pragma unroll
  for (int off = 32; off; off >>= 1) x += __shfl_xor(x, off, 64);
  return x;
}

__device__ __forceinline__ float silu_f(float x) { return x / (1.0f + __expf(-x)); }

// reduce 16 partials across a 16-lane group; lane l16 gets total of index l16
__device__ __forceinline__ float reduce_scatter16(const float pu[16], int l16) {
  float r8[8];
#pragma unroll
  for (int u = 0; u < 8; ++u) {
    const float keep = (l16 & 8) ? pu[u + 8] : pu[u];
    const float send = (l16 & 8) ? pu[u] : pu[u + 8];
    r8[u] = keep + __shfl_xor(send, 8, 64);
  }
  float r4[4];
#pragma unroll
  for (int u = 0; u < 4; ++u) {
    const float keep = (l16 & 4) ? r8[u + 4] : r8[u];
    const float send = (l16 & 4) ? r8[u] : r8[u + 4];
    r4[u] = keep + __shfl_xor(send, 4, 64);
  }
  float r2[2];
#pragma unroll
  for (int u = 0; u < 2; ++u) {
    const float keep = (l16 & 2) ? r4[u + 2] : r4[u];
    const float send = (l16 & 2) ? r4[u] : r4[u + 2];
    r2[u] = keep + __shfl_xor(send, 2, 64);
  }
  const float keep = (l16 & 1) ? r2[1] : r2[0];
  const float send = (l16 & 1) ? r2[0] : r2[1];
  return keep + __shfl_xor(send, 1, 64);
}

// ---------------------------------------------------------------- embed
__global__ __launch_bounds__(128) void embed_kernel(
    const float* __restrict__ node_h,
    const float* __restrict__ W1, const float* __restrict__ b1,
    const float* __restrict__ W2, const float* __restrict__ b2,
    const float* __restrict__ g, const float* __restrict__ b,
    float* __restrict__ s, float* __restrict__ v) {
  const int n = blockIdx.x, tid = threadIdx.x;
  __shared__ float hb[IN_SZ];
  __shared__ float h1[S_DIM];
  __shared__ float red[4];
  if (tid < IN_SZ) hb[tid] = node_h[n * IN_SZ + tid];
  __syncthreads();
  float acc = b1[tid];
#pragma unroll 8
  for (int k = 0; k < IN_SZ; ++k) acc += hb[k] * W1[k * S_DIM + tid];
  float x = silu_f(acc);
  h1[tid] = x;
  __syncthreads();
  float acc2 = b2[tid];
#pragma unroll 8
  for (int k = 0; k < S_DIM; ++k) acc2 += h1[k] * W2[k * S_DIM + tid];
  float y = silu_f(acc2);
  const int wv = tid >> 6, lane = tid & 63;
  float sm = wave_sum(y);
  float sq = wave_sum(y * y);
  if (lane == 0) { red[wv] = sm; red[2 + wv] = sq; }
  __syncthreads();
  float tot = red[0] + red[1], tot2 = red[2] + red[3];
  float mu = tot * (1.0f / 128.0f);
  float var = tot2 * (1.0f / 128.0f) - mu * mu;
  float inv = rsqrtf(var + LN_EPS);
  s[n * S_DIM + tid] = (y - mu) * inv * g[tid] + b[tid];
  if (tid < 48) v[n * 48 + tid] = 0.0f;
}

// ---------------------------------------------------------------- sort infra
__global__ __launch_bounds__(256) void hist_kernel(const int* __restrict__ edst,
                                                   int* __restrict__ cnt) {
  int e = blockIdx.x * 256 + threadIdx.x;
  if (e < N_EDGES) atomicAdd(&cnt[edst[e]], 1);
}

__global__ __launch_bounds__(1024) void scan_kernel(const int* __restrict__ cnt,
                                                    int* __restrict__ rowptr) {
  __shared__ int wsum[16];
  __shared__ int carry_s;
  const int t = threadIdx.x, w = t >> 6, ln = t & 63;
  if (t == 0) carry_s = 0;
  __syncthreads();
  for (int base = 0; base < N_NODES; base += 1024) {
    const int idx = base + t;
    const int x = (idx < N_NODES) ? cnt[idx] : 0;
    int incl = x;
#pragma unroll
    for (int off = 1; off < 64; off <<= 1) {
      const int y = __shfl_up(incl, off, 64);
      if (ln >= off) incl += y;
    }
    if (ln == 63) wsum[w] = incl;
    __syncthreads();
    int woff = 0;
    for (int k = 0; k < w; ++k) woff += wsum[k];
    const int carry = carry_s;
    if (idx < N_NODES) rowptr[idx] = carry + woff + incl - x;
    __syncthreads();
    if (t == 1023) carry_s = carry + woff + incl;
    __syncthreads();
  }
  if (threadIdx.x == 0) rowptr[N_NODES] = carry_s;
}

__global__ __launch_bounds__(256) void initcur_kernel(const int* __restrict__ rowptr,
                                                      int* __restrict__ cursor) {
  int i = blockIdx.x * 256 + threadIdx.x;
  if (i < N_NODES) cursor[i] = rowptr[i];
}

__global__ __launch_bounds__(256) void scatter_kernel(const int* __restrict__ esrc,
                                                      const int* __restrict__ edst,
                                                      int* __restrict__ cursor,
                                                      int* __restrict__ srcs,
                                                      int* __restrict__ dsts) {
  int e = blockIdx.x * 256 + threadIdx.x;
  if (e < N_EDGES) {
    const int d = edst[e];
    const int p = atomicAdd(&cursor[d], 1);
    srcs[p] = esrc[e];
    dsts[p] = d;
  }
}

// ---------------------------------------------------------------- edge GEMM
// 64 edges per 256-thread block (dst-sorted when scratch allows).
// thread tile: eg = t>>4 owns edges eg*4..eg*4+3; cols {l16*4..+3, 64+l16*4..+3}
__global__ __launch_bounds__(256) void edge_gemm_kernel(
    const float* __restrict__ s, const float* __restrict__ v,
    const float* __restrict__ coords,
    const int* __restrict__ srcs, const int* __restrict__ dsts,
    float* __restrict__ smsg, float* __restrict__ vmsg,
    const float* __restrict__ Wh, const float* __restrict__ Wu,
    const float* __restrict__ Ws, const float* __restrict__ bs,
    const float* __restrict__ Wg, const float* __restrict__ bg,
    const float* __restrict__ lng, const float* __restrict__ lnb) {
  __shared__ float L[LDS_F];
  const int t = threadIdx.x;
  const int wv = t >> 6, ln = t & 63;
  const int eg = t >> 4, l16 = t & 15;
  const int e0 = blockIdx.x * TE;
  int* stile = (int*)&L[ST_O];
  int* dtile = (int*)&L[DT_O];
  if (t < TE) { stile[t] = srcs[e0 + t]; dtile[t] = dsts[e0 + t]; }
  for (int k = t; k < H_DIM * H_DIM; k += 256) L[WHL_O + k] = Wh[k];
  for (int k = t; k < H_DIM * V_DIM; k += 256) L[WUL_O + k] = Wu[k];
  __syncthreads();

  const int zsrc = stile[t >> 2];  // src node for z staging (t>>2 = edge)

  // P1a: gather v_e (transposed [c][vv], vv=0 xdiff, 1..16 v) for wave's 16 edges
  const int lc = ln % 3, lq = ln / 3;  // for ln<48: channel lq, coord lc
  for (int i = 0; i < 16; ++i) {
    const int e = wv * 16 + i;
    const int src = stile[e];
    if (ln < 48) {
      L[A_O + e * 60 + lc * 20 + lq + 1] = v[(size_t)src * 48 + ln];
    } else if (ln < 51) {
      const int c = ln - 48;
      L[A_O + e * 60 + c * 20 + 0] = coords[src * 3 + c] - coords[dtile[e] * 3 + c];
    }
  }
  __syncthreads();

  // P1b: vh_t[c][h] = sum_vv ve_t[c][vv] * Wh[vv][h]   (h=lq, c=lc for ln<51)
  {
    float wh[H_DIM];
    if (ln < 51) {
#pragma unroll
      for (int vv = 0; vv < H_DIM; ++vv) wh[vv] = L[WHL_O + vv * H_DIM + lq];
    }
    for (int i = 0; i < 16; ++i) {
      const int e = wv * 16 + i;
      if (ln < 51) {
        const int base = A_O + e * 60 + lc * 20;
        const float4 v0 = *(const float4*)&L[base + 0];
        const float4 v1 = *(const float4*)&L[base + 4];
        const float4 v2 = *(const float4*)&L[base + 8];
        const float4 v3 = *(const float4*)&L[base + 12];
        const float vl = L[base + 16];
        float a = wh[0] * v0.x + wh[1] * v0.y + wh[2] * v0.z + wh[3] * v0.w
                + wh[4] * v1.x + wh[5] * v1.y + wh[6] * v1.z + wh[7] * v1.w
                + wh[8] * v2.x + wh[9] * v2.y + wh[10] * v2.z + wh[11] * v2.w
                + wh[12] * v3.x + wh[13] * v3.y + wh[14] * v3.z + wh[15] * v3.w
                + wh[16] * vl;
        L[B_O + e * 60 + lc * 20 + lq] = a;
      }
    }
  }
  __syncthreads();

  // P1c: sh[h] = |vh[h]|  (into SH2, A region — VE dead)
  for (int i = 0; i < 16; ++i) {
    const int e = wv * 16 + i;
    if (ln < H_DIM) {
      const float x0 = L[B_O + e * 60 + 0 + ln];
      const float x1 = L[B_O + e * 60 + 20 + ln];
      const float x2 = L[B_O + e * 60 + 40 + ln];
      L[SH2_O + e * 17 + ln] = sqrtf(x0 * x0 + x1 * x1 + x2 * x2 + GVP_EPS);
    }
  }
  // P1d: vu[u][c] = sum_h vh_t[c][h] * Wu[h][u]  (no barrier needed vs P1c: disjoint)
  {
    float wu[H_DIM];
    if (ln < 48) {
#pragma unroll
      for (int h = 0; h < H_DIM; ++h) wu[h] = L[WUL_O + h * V_DIM + lq];
    }
    for (int i = 0; i < 16; ++i) {
      const int e = wv * 16 + i;
      if (ln < 48) {
        const int base = B_O + e * 60 + lc * 20;
        const float4 v0 = *(const float4*)&L[base + 0];
        const float4 v1 = *(const float4*)&L[base + 4];
        const float4 v2 = *(const float4*)&L[base + 8];
        const float4 v3 = *(const float4*)&L[base + 12];
        const float vl = L[base + 16];
        float a = wu[0] * v0.x + wu[1] * v0.y + wu[2] * v0.z + wu[3] * v0.w
                + wu[4] * v1.x + wu[5] * v1.y + wu[6] * v1.z + wu[7] * v1.w
                + wu[8] * v2.x + wu[9] * v2.y + wu[10] * v2.z + wu[11] * v2.w
                + wu[12] * v3.x + wu[13] * v3.y + wu[14] * v3.z + wu[15] * v3.w
                + wu[16] * vl;
        L[VU_O + e * 48 + lq * 3 + lc] = a;
      }
    }
  }

  // P2: feats GEMM  z[145] @ Ws[145][128]; acc cols {l16*4..+3, 64+l16*4..+3}
  float acc[4][8];
  {
    const float4 b0 = *(const float4*)&bs[l16 * 4];
    const float4 b1 = *(const float4*)&bs[64 + l16 * 4];
#pragma unroll
    for (int i = 0; i < 4; ++i) {
      acc[i][0] = b0.x; acc[i][1] = b0.y; acc[i][2] = b0.z; acc[i][3] = b0.w;
      acc[i][4] = b1.x; acc[i][5] = b1.y; acc[i][6] = b1.z; acc[i][7] = b1.w;
    }
  }
  for (int kc = 0; kc < 9; ++kc) {
    __syncthreads();
    {  // stage Ws rows kc*16..+15 into WSC [16][132] (+row 144 -> row 16 on last)
      const int r = t >> 4;
      const float* gsrc = &Ws[(size_t)(kc * 16 + r) * S_DIM];
      const float4 a0 = *(const float4*)(gsrc + l16 * 4);
      const float4 a1 = *(const float4*)(gsrc + 64 + l16 * 4);
      *(float4*)&L[WSC_O + r * WSTR + l16 * 4] = a0;
      *(float4*)&L[WSC_O + r * WSTR + 64 + l16 * 4] = a1;
      if (kc == 8 && t < 128) L[WSC_O + 16 * WSTR + t] = Ws[144 * S_DIM + t];
    }
    {  // stage z chunk into ZL [64][20]
      const int e = t >> 2, q = t & 3;
      if (kc < 8) {
        const float4 zz = *(const float4*)&s[(size_t)zsrc * S_DIM + kc * 16 + q * 4];
        *(float4*)&L[ZL_O + e * 20 + q * 4] = zz;
      } else {
        float4 zz;
        zz.x = L[SH2_O + e * 17 + q * 4 + 0];
        zz.y = L[SH2_O + e * 17 + q * 4 + 1];
        zz.z = L[SH2_O + e * 17 + q * 4 + 2];
        zz.w = L[SH2_O + e * 17 + q * 4 + 3];
        *(float4*)&L[ZL_O + e * 20 + q * 4] = zz;
        if (q == 0) L[ZL_O + e * 20 + 16] = L[SH2_O + e * 17 + 16];
      }
    }
    __syncthreads();
#pragma unroll
    for (int kq = 0; kq < 4; ++kq) {
      float4 z4[4];
#pragma unroll
      for (int i = 0; i < 4; ++i)
        z4[i] = *(const float4*)&L[ZL_O + (eg * 4 + i) * 20 + kq * 4];
#pragma unroll
      for (int j = 0; j < 4; ++j) {
        const int kk = kq * 4 + j;
        const float4 w0 = *(const float4*)&L[WSC_O + kk * WSTR + l16 * 4];
        const float4 w1 = *(const float4*)&L[WSC_O + kk * WSTR + 64 + l16 * 4];
#pragma unroll
        for (int i = 0; i < 4; ++i) {
          const float z = (j == 0) ? z4[i].x : (j == 1) ? z4[i].y : (j == 2) ? z4[i].z : z4[i].w;
          acc[i][0] += z * w0.x; acc[i][1] += z * w0.y;
          acc[i][2] += z * w0.z; acc[i][3] += z * w0.w;
          acc[i][4] += z * w1.x; acc[i][5] += z * w1.y;
          acc[i][6] += z * w1.z; acc[i][7] += z * w1.w;
        }
      }
    }
  }
  {  // k = 144 tail (z = sh[16] staged at ZL[e][16]; Ws row at WSC row 16)
    const float4 w0 = *(const float4*)&L[WSC_O + 16 * WSTR + l16 * 4];
    const float4 w1 = *(const float4*)&L[WSC_O + 16 * WSTR + 64 + l16 * 4];
#pragma unroll
    for (int i = 0; i < 4; ++i) {
      const float z = L[ZL_O + (eg * 4 + i) * 20 + 16];
      acc[i][0] += z * w0.x; acc[i][1] += z * w0.y;
      acc[i][2] += z * w0.z; acc[i][3] += z * w0.w;
      acc[i][4] += z * w1.x; acc[i][5] += z * w1.y;
      acc[i][6] += z * w1.z; acc[i][7] += z * w1.w;
    }
  }
  __syncthreads();
  {  // stage Wg transposed: WgT[16][128] at A (Ws chunks + SH2 dead)
    const float4 g0 = *(const float4*)&Wg[t * 8];
    const float4 g1 = *(const float4*)&Wg[t * 8 + 4];
    const int row = t >> 1, u0 = (t & 1) * 8;
    L[WGT_O + (u0 + 0) * 128 + row] = g0.x;
    L[WGT_O + (u0 + 1) * 128 + row] = g0.y;
    L[WGT_O + (u0 + 2) * 128 + row] = g0.z;
    L[WGT_O + (u0 + 3) * 128 + row] = g0.w;
    L[WGT_O + (u0 + 4) * 128 + row] = g1.x;
    L[WGT_O + (u0 + 5) * 128 + row] = g1.y;
    L[WGT_O + (u0 + 6) * 128 + row] = g1.z;
    L[WGT_O + (u0 + 7) * 128 + row] = g1.w;
  }
  // silu -> feats (registers only; safe across barrier)
#pragma unroll
  for (int i = 0; i < 4; ++i)
#pragma unroll
    for (int j = 0; j < 8; ++j) acc[i][j] = silu_f(acc[i][j]);
  __syncthreads();

  // P3a: gate via WgT (conflict-free reads)
  const float bgv = bg[l16];
  float gate_i[4];
#pragma unroll
  for (int pr = 0; pr < 2; ++pr) {
    float puA[16], puB[16];
    const int pA = pr * 2, pB = pr * 2 + 1;
#pragma unroll
    for (int u = 0; u < 16; ++u) {
      const float4 wA = *(const float4*)&L[WGT_O + u * 128 + l16 * 4];
      const float4 wB = *(const float4*)&L[WGT_O + u * 128 + 64 + l16 * 4];
      puA[u] = acc[pA][0] * wA.x + acc[pA][1] * wA.y + acc[pA][2] * wA.z + acc[pA][3] * wA.w
             + acc[pA][4] * wB.x + acc[pA][5] * wB.y + acc[pA][6] * wB.z + acc[pA][7] * wB.w;
      puB[u] = acc[pB][0] * wA.x + acc[pB][1] * wA.y + acc[pB][2] * wA.z + acc[pB][3] * wA.w
             + acc[pB][4] * wB.x + acc[pB][5] * wB.y + acc[pB][6] * wB.z + acc[pB][7] * wB.w;
    }
    gate_i[pA] = silu_f(reduce_scatter16(puA, l16) + bgv);
    gate_i[pB] = silu_f(reduce_scatter16(puB, l16) + bgv);
  }
  // P3b: vector message in-place in VU: vm = vec_ln(vu*gate)*INV_Z  (u = l16)
#pragma unroll
  for (int i = 0; i < 4; ++i) {
    const int e = eg * 4 + i;
    const int base = VU_O + e * 48 + l16 * 3;
    const float g = gate_i[i];
    const float vm0 = L[base + 0] * g;
    const float vm1 = L[base + 1] * g;
    const float vm2 = L[base + 2] * g;
    float ss = vm0 * vm0 + vm1 * vm1 + vm2 * vm2;
#pragma unroll
    for (int off = 1; off < 16; off <<= 1) ss += __shfl_xor(ss, off, 64);
    const float sc = INV_Z * rsqrtf(ss * (1.0f / 16.0f) + GVP_EPS);
    L[base + 0] = vm0 * sc;
    L[base + 1] = vm1 * sc;
    L[base + 2] = vm2 * sc;
  }
  __syncthreads();  // WgT consumed; SM may now overlay A..ZL

  // P3c: scalar message = LN(feats)*lng+lnb scaled, into SM (stride 132, XOR swz)
  const float4 lgA = *(const float4*)&lng[l16 * 4];
  const float4 lgB = *(const float4*)&lng[64 + l16 * 4];
  const float4 lbA = *(const float4*)&lnb[l16 * 4];
  const float4 lbB = *(const float4*)&lnb[64 + l16 * 4];
#pragma unroll
  for (int i = 0; i < 4; ++i) {
    float s1 = 0.0f, s2 = 0.0f;
#pragma unroll
    for (int j = 0; j < 8; ++j) { s1 += acc[i][j]; s2 += acc[i][j] * acc[i][j]; }
#pragma unroll
    for (int off = 1; off < 16; off <<= 1) {
      s1 += __shfl_xor(s1, off, 64);
      s2 += __shfl_xor(s2, off, 64);
    }
    const float mu = s1 * (1.0f / 128.0f);
    const float var = s2 * (1.0f / 128.0f) - mu * mu;
    const float inv = rsqrtf(var + LN_EPS);
    const int e = eg * 4 + i;
    const int swz = (e & 7) << 2;
    const int col0 = (l16 * 4) ^ swz;
    float4 o0, o1;
    o0.x = ((acc[i][0] - mu) * inv * lgA.x + lbA.x) * INV_Z;
    o0.y = ((acc[i][1] - mu) * inv * lgA.y + lbA.y) * INV_Z;
    o0.z = ((acc[i][2] - mu) * inv * lgA.z + lbA.z) * INV_Z;
    o0.w = ((acc[i][3] - mu) * inv * lgA.w + lbA.w) * INV_Z;
    o1.x = ((acc[i][4] - mu) * inv * lgB.x + lbB.x) * INV_Z;
    o1.y = ((acc[i][5] - mu) * inv * lgB.y + lbB.y) * INV_Z;
    o1.z = ((acc[i][6] - mu) * inv * lgB.z + lbB.z) * INV_Z;
    o1.w = ((acc[i][7] - mu) * inv * lgB.w + lbB.w) * INV_Z;
    *(float4*)&L[SM_O + e * SMSTR + col0] = o0;
    *(float4*)&L[SM_O + e * SMSTR + 64 + col0] = o1;
  }
  __syncthreads();

  // P4: per-dst-run aggregation, one atomic per (run, component)
  int r = 0;
  while (r < TE) {
    const int d = dtile[r];
    int rend = r + 1;
    while (rend < TE && dtile[rend] == d) ++rend;
    if (t < 128) {
      float a = 0.0f;
      for (int i = r; i < rend; ++i)
        a += L[SM_O + i * SMSTR + (t ^ ((i & 7) << 2))];
      atomicAdd(&smsg[(size_t)d * S_DIM + t], a);
    } else if (t < 176) {
      const int c = t - 128;
      float a = 0.0f;
      for (int i = r; i < rend; ++i) a += L[VU_O + i * 48 + c];
      atomicAdd(&vmsg[(size_t)d * 48 + c], a);
    }
    r = rend;
  }
}

// ---------------------------------------------------------------- node update
__global__ __launch_bounds__(256) void node_update_kernel(
    float* __restrict__ s, float* __restrict__ v,
    const float* __restrict__ smsg, const float* __restrict__ vmsg,
    const float* __restrict__ Wh, const float* __restrict__ Wu,
    const float* __restrict__ Ws, const float* __restrict__ bs,
    const float* __restrict__ Wg, const float* __restrict__ bg,
    const float* __restrict__ lng, const float* __restrict__ lnb,
    const float* __restrict__ og, const float* __restrict__ ob) {
  const int wv = threadIdx.x >> 6, lane = threadIdx.x & 63;
  const int n = blockIdx.x * 4 + wv;

  __shared__ float z[4][146];
  __shared__ float vel[4][48];
  __shared__ float vhl[4][48];
  __shared__ float fe[4][128];
  __shared__ float ga[4][16];

  float s0 = s[n * S_DIM + lane] + smsg[n * S_DIM + lane];
  float s1 = s[n * S_DIM + 64 + lane] + smsg[n * S_DIM + 64 + lane];
  float sm_ = wave_sum(s0 + s1), sq_ = wave_sum(s0 * s0 + s1 * s1);
  float mu = sm_ * (1.0f / 128.0f), var = sq_ * (1.0f / 128.0f) - mu * mu;
  float inv = rsqrtf(var + LN_EPS);
  float sa0 = (s0 - mu) * inv * og[lane] + ob[lane];
  float sa1 = (s1 - mu) * inv * og[64 + lane] + ob[64 + lane];
  z[wv][lane] = sa0; z[wv][64 + lane] = sa1;
  float vvr = 0.0f;
  if (lane < 48) vvr = v[n * 48 + lane] + vmsg[n * 48 + lane];
  float n2 = wave_sum(vvr * vvr);
  float rms = sqrtf(n2 * (1.0f / 16.0f) + GVP_EPS);
  float vln = vvr / rms;
  if (lane < 48) vel[wv][lane] = vln;
  __syncthreads();

  if (lane < 48) {
    int h = lane / 3, c = lane - 3 * h;
    float a = 0.0f;
#pragma unroll
    for (int vv = 0; vv < V_DIM; ++vv) a += vel[wv][vv * 3 + c] * Wh[vv * V_DIM + h];
    vhl[wv][lane] = a;
  }
  __syncthreads();

  if (lane < V_DIM) {
    float a = vhl[wv][lane * 3], b_ = vhl[wv][lane * 3 + 1], c_ = vhl[wv][lane * 3 + 2];
    z[wv][128 + lane] = sqrtf(a * a + b_ * b_ + c_ * c_ + GVP_EPS);
  }
  float vur = 0.0f;
  if (lane < 48) {
    int u = lane / 3, c = lane - 3 * u;
#pragma unroll
    for (int h = 0; h < V_DIM; ++h) vur += vhl[wv][h * 3 + c] * Wu[h * V_DIM + u];
  }
  __syncthreads();

  float f0 = bs[lane], f1 = bs[64 + lane];
#pragma unroll 4
  for (int k = 0; k < 144; ++k) {
    float zz = z[wv][k];
    f0 += zz * Ws[k * S_DIM + lane];
    f1 += zz * Ws[k * S_DIM + 64 + lane];
  }
  f0 = silu_f(f0); f1 = silu_f(f1);
  fe[wv][lane] = f0; fe[wv][64 + lane] = f1;
  __syncthreads();

  {
    int u = lane >> 2, q = lane & 3;
    float p = 0.0f;
#pragma unroll 8
    for (int k = q * 32; k < q * 32 + 32; ++k) p += fe[wv][k] * Wg[k * V_DIM + u];
    p += __shfl_xor(p, 1, 64);
    p += __shfl_xor(p, 2, 64);
    if (q == 0) ga[wv][u] = silu_f(p + bg[u]);
  }
  float sm2 = wave_sum(f0 + f1), sq2 = wave_sum(f0 * f0 + f1 * f1);
  float mu2 = sm2 * (1.0f / 128.0f), var2 = sq2 * (1.0f / 128.0f) - mu2 * mu2;
  float inv2 = rsqrtf(var2 + LN_EPS);
  float t0 = sa0 + (f0 - mu2) * inv2 * lng[lane] + lnb[lane];
  float t1 = sa1 + (f1 - mu2) * inv2 * lng[64 + lane] + lnb[64 + lane];
  float sm3 = wave_sum(t0 + t1), sq3 = wave_sum(t0 * t0 + t1 * t1);
  float mu3 = sm3 * (1.0f / 128.0f), var3 = sq3 * (1.0f / 128.0f) - mu3 * mu3;
  float inv3 = rsqrtf(var3 + LN_EPS);
  s[n * S_DIM + lane] = (t0 - mu3) * inv3 * og[lane] + ob[lane];
  s[n * S_DIM + 64 + lane] = (t1 - mu3) * inv3 * og[64 + lane] + ob[64 + lane];
  __syncthreads();

  float vo = 0.0f;
  if (lane < 48) { int u = lane / 3; vo = vur * ga[wv][u]; }
  float n22 = wave_sum(vo * vo);
  float rms2 = sqrtf(n22 * (1.0f / 16.0f) + GVP_EPS);
  float vr = vo / rms2;
  float v2 = (lane < 48) ? (vln + vr) : 0.0f;
  float n23 = wave_sum(v2 * v2);
  float rms3 = sqrtf(n23 * (1.0f / 16.0f) + GVP_EPS);
  if (lane < 48) v[n * 48 + lane] = v2 / rms3;
}

// ---------------------------------------------------------------- launch
extern "C" void kernel_launch(void* const* d_in, const int* in_sizes, int n_in,
                              void* d_out, int out_size, void* d_ws, size_t ws_size,
                              hipStream_t stream) {
  const float* node_h = (const float*)d_in[0];
  const float* coords = (const float*)d_in[1];
  const int* esrc = (const int*)d_in[2];
  const int* edst = (const int*)d_in[3];
  const float* emb_W1 = (const float*)d_in[4];
  const float* emb_b1 = (const float*)d_in[5];
  const float* emb_W2 = (const float*)d_in[6];
  const float* emb_b2 = (const float*)d_in[7];
  const float* norm_g = (const float*)d_in[8];
  const float* norm_b = (const float*)d_in[9];
  const float* em_Wh = (const float*)d_in[10];
  const float* em_Wu = (const float*)d_in[11];
  const float* em_Ws = (const float*)d_in[12];
  const float* em_bs = (const float*)d_in[13];
  const float* em_Wg = (const float*)d_in[14];
  const float* em_bg = (const float*)d_in[15];
  const float* em_lng = (const float*)d_in[16];
  const float* em_lnb = (const float*)d_in[17];
  const float* nu_Wh = (const float*)d_in[18];
  const float* nu_Wu = (const float*)d_in[19];
  const float* nu_Ws = (const float*)d_in[20];
  const float* nu_bs = (const float*)d_in[21];
  const float* nu_Wg = (const float*)d_in[22];
  const float* nu_bg = (const float*)d_in[23];
  const float* nu_lng = (const float*)d_in[24];
  const float* nu_lnb = (const float*)d_in[25];
  const float* ln_g = (const float*)d_in[26];
  const float* ln_b = (const float*)d_in[27];

  float* s = (float*)d_out;                      // [N,128] output 0
  float* v = s + (size_t)N_NODES * S_DIM;        // [N,16,3] output 1

  float* smsg = (float*)d_ws;                    // [N,128]
  float* vmsg = smsg + (size_t)N_NODES * S_DIM;  // [N,48]
  int* rowptr = (int*)(vmsg + (size_t)N_NODES * 48);  // [N+1] (+pad)
  int* srcs = rowptr + N_NODES + 8;              // [E]
  int* dsts = srcs + N_EDGES;                    // [E]
  int* cnt = (int*)smsg;                         // alias (setup phase only)
  int* cursor = cnt + N_NODES;                   // alias (setup phase only)

  // Scratch needed for the sorted path: msg buffers + rowptr + srcs + dsts.
  const size_t need_sorted =
      (size_t)N_NODES * 176 * sizeof(float) +
      (size_t)(N_NODES + 1 + 8) * sizeof(int) +
      (size_t)2 * N_EDGES * sizeof(int);
  // ws_size is fixed across calls -> branch is deterministic (graph-safe).
  const bool use_sorted = ws_size >= need_sorted;

  if (use_sorted) {
    // ---- dst-sort setup (edge list is a launch input; recomputed every call)
    hipMemsetAsync(cnt, 0, N_NODES * sizeof(int), stream);
    hist_kernel<<<(N_EDGES + 255) / 256, 256, 0, stream>>>(edst, cnt);
    scan_kernel<<<1, 1024, 0, stream>>>(cnt, rowptr);
    initcur_kernel<<<(N_NODES + 255) / 256, 256, 0, stream>>>(rowptr, cursor);
    scatter_kernel<<<(N_EDGES + 255) / 256, 256, 0, stream>>>(esrc, edst, cursor, srcs, dsts);
  }
  const int* esrc_use = use_sorted ? srcs : esrc;
  const int* edst_use = use_sorted ? dsts : edst;

  embed_kernel<<<N_NODES, 128, 0, stream>>>(node_h, emb_W1, emb_b1, emb_W2, emb_b2,
                                            norm_g, norm_b, s, v);
  for (int i = 0; i < 3; ++i) {
    hipMemsetAsync(smsg, 0, (size_t)N_NODES * 176 * sizeof(float), stream);
    edge_gemm_kernel<<<N_EDGES / TE, 256, 0, stream>>>(
        s, v, coords, esrc_use, edst_use, smsg, vmsg,
        em_Wh + i * H_DIM * H_DIM, em_Wu + i * H_DIM * V_DIM,
        em_Ws + i * 145 * S_DIM, em_bs + i * S_DIM,
        em_Wg + i * S_DIM * V_DIM, em_bg + i * V_DIM,
        em_lng + i * S_DIM, em_lnb + i * S_DIM);
    node_update_kernel<<<N_NODES / 4, 256, 0, stream>>>(
        s, v, smsg, vmsg,
        nu_Wh + i * V_DIM * V_DIM, nu_Wu + i * V_DIM * V_DIM,
        nu_Ws + i * 144 * S_DIM, nu_bs + i * S_DIM,
        nu_Wg + i * S_DIM * V_DIM, nu_bg + i * V_DIM,
        nu_lng + i * S_DIM, nu_lnb + i * S_DIM,
        ln_g + i * S_DIM, ln_b + i * S_DIM);
  }
}

// Round 9
// 3894.738 us; speedup vs baseline: 1.5479x; 1.5479x over previous
//
#include <hip/hip_runtime.h>
#include <math.h>

#define N_NODES 25000
#define N_EDGES 800000
#define IN_SZ 64
#define S_DIM 128
#define V_DIM 16
#define H_DIM 17
#define GVP_EPS 1e-8f
#define LN_EPS 1e-5f
#define INV_Z 0.1f
#define TE 64  // edges per block (16 per wave)

// ---- LDS layout (float offsets) ----
// ZF [64][148] per-edge row: P1 scratch ve[3][20]@0, vh[3][20]@64, sh@128..144;
//              then z (s-cols 0..127 overwrite 0..127, sh stays); then SM overlay 0..127.
// VU [64][48]; WhL 289; WuL 272; stile/dtile int[64] each.
#define ZF_O 0
#define ZSTR 148
#define VU_O 9472
#define WHL_O 12544
#define WUL_O 12833
#define ST_O 13105
#define DT_O 13169
#define LDS_F 13233  // 52932 B -> 3 blocks/CU

__device__ __forceinline__ float wave_sum(float x) {
#pragma unroll
  for (int off = 32; off; off >>= 1) x += __shfl_xor(x, off, 64);
  return x;
}

__device__ __forceinline__ float sum16(float x) {
#pragma unroll
  for (int off = 1; off < 16; off <<= 1) x += __shfl_xor(x, off, 64);
  return x;
}

__device__ __forceinline__ float silu_f(float x) { return x / (1.0f + __expf(-x)); }

// wave-local DS ordering fence (DS ops are in-order per wave; this pins the compiler)
__device__ __forceinline__ void lds_fence() {
  asm volatile("s_waitcnt lgkmcnt(0)" ::: "memory");
}

// reduce 16 partials across a 16-lane group; lane l16 gets total of index l16
__device__ __forceinline__ float reduce_scatter16(const float pu[16], int l16) {
  float r8[8];
#pragma unroll
  for (int u = 0; u < 8; ++u) {
    const float keep = (l16 & 8) ? pu[u + 8] : pu[u];
    const float send = (l16 & 8) ? pu[u] : pu[u + 8];
    r8[u] = keep + __shfl_xor(send, 8, 64);
  }
  float r4[4];
#pragma unroll
  for (int u = 0; u < 4; ++u) {
    const float keep = (l16 & 4) ? r8[u + 4] : r8[u];
    const float send = (l16 & 4) ? r8[u] : r8[u + 4];
    r4[u] = keep + __shfl_xor(send, 4, 64);
  }
  float r2[2];
#pragma unroll
  for (int u = 0; u < 2; ++u) {
    const float keep = (l16 & 2) ? r4[u + 2] : r4[u];
    const float send = (l16 & 2) ? r4[u] : r4[u + 2];
    r2[u] = keep + __shfl_xor(send, 2, 64);
  }
  const float keep = (l16 & 1) ? r2[1] : r2[0];
  const float send = (l16 & 1) ? r2[0] : r2[1];
  return keep + __shfl_xor(send, 1, 64);
}

// ---------------------------------------------------------------- embed
__global__ __launch_bounds__(128) void embed_kernel(
    const float* __restrict__ node_h,
    const float* __restrict__ W1, const float* __restrict__ b1,
    const float* __restrict__ W2, const float* __restrict__ b2,
    const float* __restrict__ g, const float* __restrict__ b,
    float* __restrict__ s, float* __restrict__ v) {
  const int n = blockIdx.x, tid = threadIdx.x;
  __shared__ float hb[IN_SZ];
  __shared__ float h1[S_DIM];
  __shared__ float red[4];
  if (tid < IN_SZ) hb[tid] = node_h[n * IN_SZ + tid];
  __syncthreads();
  float acc = b1[tid];
#pragma unroll 8
  for (int k = 0; k < IN_SZ; ++k) acc += hb[k] * W1[k * S_DIM + tid];
  float x = silu_f(acc);
  h1[tid] = x;
  __syncthreads();
  float acc2 = b2[tid];
#pragma unroll 8
  for (int k = 0; k < S_DIM; ++k) acc2 += h1[k] * W2[k * S_DIM + tid];
  float y = silu_f(acc2);
  const int wv = tid >> 6, lane = tid & 63;
  float sm = wave_sum(y);
  float sq = wave_sum(y * y);
  if (lane == 0) { red[wv] = sm; red[2 + wv] = sq; }
  __syncthreads();
  float tot = red[0] + red[1], tot2 = red[2] + red[3];
  float mu = tot * (1.0f / 128.0f);
  float var = tot2 * (1.0f / 128.0f) - mu * mu;
  float inv = rsqrtf(var + LN_EPS);
  s[n * S_DIM + tid] = (y - mu) * inv * g[tid] + b[tid];
  if (tid < 48) v[n * 48 + tid] = 0.0f;
}

// ---------------------------------------------------------------- sort infra
__global__ __launch_bounds__(256) void hist_kernel(const int* __restrict__ edst,
                                                   int* __restrict__ cnt) {
  int e = blockIdx.x * 256 + threadIdx.x;
  if (e < N_EDGES) atomicAdd(&cnt[edst[e]], 1);
}

__global__ __launch_bounds__(1024) void scan_kernel(const int* __restrict__ cnt,
                                                    int* __restrict__ rowptr) {
  __shared__ int wsum[16];
  __shared__ int carry_s;
  const int t = threadIdx.x, w = t >> 6, ln = t & 63;
  if (t == 0) carry_s = 0;
  __syncthreads();
  for (int base = 0; base < N_NODES; base += 1024) {
    const int idx = base + t;
    const int x = (idx < N_NODES) ? cnt[idx] : 0;
    int incl = x;
#pragma unroll
    for (int off = 1; off < 64; off <<= 1) {
      const int y = __shfl_up(incl, off, 64);
      if (ln >= off) incl += y;
    }
    if (ln == 63) wsum[w] = incl;
    __syncthreads();
    int woff = 0;
    for (int k = 0; k < w; ++k) woff += wsum[k];
    const int carry = carry_s;
    if (idx < N_NODES) rowptr[idx] = carry + woff + incl - x;
    __syncthreads();
    if (t == 1023) carry_s = carry + woff + incl;
    __syncthreads();
  }
  if (threadIdx.x == 0) rowptr[N_NODES] = carry_s;
}

__global__ __launch_bounds__(256) void initcur_kernel(const int* __restrict__ rowptr,
                                                      int* __restrict__ cursor) {
  int i = blockIdx.x * 256 + threadIdx.x;
  if (i < N_NODES) cursor[i] = rowptr[i];
}

__global__ __launch_bounds__(256) void scatter_kernel(const int* __restrict__ esrc,
                                                      const int* __restrict__ edst,
                                                      int* __restrict__ cursor,
                                                      int* __restrict__ srcs,
                                                      int* __restrict__ dsts) {
  int e = blockIdx.x * 256 + threadIdx.x;
  if (e < N_EDGES) {
    const int d = edst[e];
    const int p = atomicAdd(&cursor[d], 1);
    srcs[p] = esrc[e];
    dsts[p] = d;
  }
}

// ---------------------------------------------------------------- edge kernel
// Wave-independent: each wave owns 16 edges end-to-end; one block barrier total.
// GEMM tile per lane: 4 edges (group g=ln>>4) x 8 cols {l16*4..+3, 64+l16*4..+3}.
__global__ __launch_bounds__(256, 3) void edge_gemm_kernel(
    const float* __restrict__ s, const float* __restrict__ v,
    const float* __restrict__ coords,
    const int* __restrict__ srcs, const int* __restrict__ dsts,
    float* __restrict__ smsg, float* __restrict__ vmsg,
    const float* __restrict__ Wh, const float* __restrict__ Wu,
    const float* __restrict__ Ws, const float* __restrict__ bs,
    const float* __restrict__ Wg, const float* __restrict__ bg,
    const float* __restrict__ lng, const float* __restrict__ lnb) {
  __shared__ float L[LDS_F];
  const int t = threadIdx.x;
  const int wv = t >> 6, ln = t & 63;
  const int g = ln >> 4, l16 = ln & 15;
  const int e0 = blockIdx.x * TE;
  int* stile = (int*)&L[ST_O];
  int* dtile = (int*)&L[DT_O];
  if (t < TE) { stile[t] = srcs[e0 + t]; dtile[t] = dsts[e0 + t]; }
  for (int k = t; k < H_DIM * H_DIM; k += 256) L[WHL_O + k] = Wh[k];
  for (int k = t; k < H_DIM * V_DIM; k += 256) L[WUL_O + k] = Wu[k];
  __syncthreads();  // the ONLY block barrier

  const int ew0 = wv * 16;          // wave's first block-local edge
  const int lc = ln % 3, lq = ln / 3;

  // ---- P1a: gather ve (transposed [c][20]) into ZF[e][0..59]
  for (int i = 0; i < 16; ++i) {
    const int e = ew0 + i, src = stile[e];
    if (ln < 48) {
      L[ZF_O + e * ZSTR + lc * 20 + lq + 1] = v[(size_t)src * 48 + ln];
    } else if (ln < 51) {
      const int c = ln - 48;
      L[ZF_O + e * ZSTR + c * 20] = coords[src * 3 + c] - coords[dtile[e] * 3 + c];
    }
  }
  lds_fence();

  // ---- P1b: vh (into ZF[e][64..123])
  {
    float wh[H_DIM];
    if (ln < 51) {
#pragma unroll
      for (int vv = 0; vv < H_DIM; ++vv) wh[vv] = L[WHL_O + vv * H_DIM + lq];
    }
    for (int i = 0; i < 16; ++i) {
      const int e = ew0 + i;
      if (ln < 51) {
        const int b = ZF_O + e * ZSTR + lc * 20;
        const float4 v0 = *(const float4*)&L[b + 0];
        const float4 v1 = *(const float4*)&L[b + 4];
        const float4 v2 = *(const float4*)&L[b + 8];
        const float4 v3 = *(const float4*)&L[b + 12];
        const float vl = L[b + 16];
        float a = wh[0] * v0.x + wh[1] * v0.y + wh[2] * v0.z + wh[3] * v0.w
                + wh[4] * v1.x + wh[5] * v1.y + wh[6] * v1.z + wh[7] * v1.w
                + wh[8] * v2.x + wh[9] * v2.y + wh[10] * v2.z + wh[11] * v2.w
                + wh[12] * v3.x + wh[13] * v3.y + wh[14] * v3.z + wh[15] * v3.w
                + wh[16] * vl;
        L[ZF_O + e * ZSTR + 64 + lc * 20 + lq] = a;
      }
    }
  }
  lds_fence();

  // ---- P1c: sh -> ZF[e][128..144]
  for (int i = 0; i < 16; ++i) {
    const int e = ew0 + i;
    if (ln < H_DIM) {
      const float x0 = L[ZF_O + e * ZSTR + 64 + 0 + ln];
      const float x1 = L[ZF_O + e * ZSTR + 64 + 20 + ln];
      const float x2 = L[ZF_O + e * ZSTR + 64 + 40 + ln];
      L[ZF_O + e * ZSTR + 128 + ln] = sqrtf(x0 * x0 + x1 * x1 + x2 * x2 + GVP_EPS);
    }
  }
  // ---- P1d: vu -> VU[e][u*3+c]  (reads vh; disjoint from P1c outputs)
  {
    float wu[H_DIM];
    if (ln < 48) {
#pragma unroll
      for (int h = 0; h < H_DIM; ++h) wu[h] = L[WUL_O + h * V_DIM + lq];
    }
    for (int i = 0; i < 16; ++i) {
      const int e = ew0 + i;
      if (ln < 48) {
        const int b = ZF_O + e * ZSTR + 64 + lc * 20;
        const float4 v0 = *(const float4*)&L[b + 0];
        const float4 v1 = *(const float4*)&L[b + 4];
        const float4 v2 = *(const float4*)&L[b + 8];
        const float4 v3 = *(const float4*)&L[b + 12];
        const float vl = L[b + 16];
        float a = wu[0] * v0.x + wu[1] * v0.y + wu[2] * v0.z + wu[3] * v0.w
                + wu[4] * v1.x + wu[5] * v1.y + wu[6] * v1.z + wu[7] * v1.w
                + wu[8] * v2.x + wu[9] * v2.y + wu[10] * v2.z + wu[11] * v2.w
                + wu[12] * v3.x + wu[13] * v3.y + wu[14] * v3.z + wu[15] * v3.w
                + wu[16] * vl;
        L[VU_O + e * 48 + lq * 3 + lc] = a;
      }
    }
  }
  lds_fence();

  // ---- Z stage: s[src] -> ZF[e][0..127] (overwrites dead ve/vh; sh stays)
  {
    const int le = ln >> 2, q = ln & 3;
    const int e = ew0 + le;
    const float* sp = &s[(size_t)stile[e] * S_DIM + q * 32];
    float* zp = &L[ZF_O + e * ZSTR + q * 32];
#pragma unroll
    for (int b = 0; b < 8; ++b)
      *(float4*)(zp + b * 4) = *(const float4*)(sp + b * 4);
  }
  lds_fence();

  // ---- P2: feats GEMM, Ws direct from global (L2-resident)
  float acc[4][8];
  {
    const float4 b0 = *(const float4*)&bs[l16 * 4];
    const float4 b1 = *(const float4*)&bs[64 + l16 * 4];
#pragma unroll
    for (int i = 0; i < 4; ++i) {
      acc[i][0] = b0.x; acc[i][1] = b0.y; acc[i][2] = b0.z; acc[i][3] = b0.w;
      acc[i][4] = b1.x; acc[i][5] = b1.y; acc[i][6] = b1.z; acc[i][7] = b1.w;
    }
  }
  const int ez = ZF_O + (ew0 + g * 4) * ZSTR;
  for (int kq = 0; kq < 36; ++kq) {
    float4 z4[4];
#pragma unroll
    for (int i = 0; i < 4; ++i)
      z4[i] = *(const float4*)&L[ez + i * ZSTR + kq * 4];
#pragma unroll
    for (int j = 0; j < 4; ++j) {
      const float* wrow = Ws + (size_t)(kq * 4 + j) * S_DIM;
      const float4 w0 = *(const float4*)(wrow + l16 * 4);
      const float4 w1 = *(const float4*)(wrow + 64 + l16 * 4);
#pragma unroll
      for (int i = 0; i < 4; ++i) {
        const float z = (j == 0) ? z4[i].x : (j == 1) ? z4[i].y : (j == 2) ? z4[i].z : z4[i].w;
        acc[i][0] += z * w0.x; acc[i][1] += z * w0.y;
        acc[i][2] += z * w0.z; acc[i][3] += z * w0.w;
        acc[i][4] += z * w1.x; acc[i][5] += z * w1.y;
        acc[i][6] += z * w1.z; acc[i][7] += z * w1.w;
      }
    }
  }
  {  // k = 144 tail (z = sh[16] at ZF[e][144])
    const float* wrow = Ws + (size_t)144 * S_DIM;
    const float4 w0 = *(const float4*)(wrow + l16 * 4);
    const float4 w1 = *(const float4*)(wrow + 64 + l16 * 4);
#pragma unroll
    for (int i = 0; i < 4; ++i) {
      const float z = L[ez + i * ZSTR + 144];
      acc[i][0] += z * w0.x; acc[i][1] += z * w0.y;
      acc[i][2] += z * w0.z; acc[i][3] += z * w0.w;
      acc[i][4] += z * w1.x; acc[i][5] += z * w1.y;
      acc[i][6] += z * w1.z; acc[i][7] += z * w1.w;
    }
  }
  // silu -> feats
#pragma unroll
  for (int i = 0; i < 4; ++i)
#pragma unroll
    for (int j = 0; j < 8; ++j) acc[i][j] = silu_f(acc[i][j]);

  // ---- P3a: gate (Wg direct from global, L1-resident 8KB), 2 edges per pass
  const float bgv = bg[l16];
  float gate_i[4];
#pragma unroll
  for (int pr = 0; pr < 2; ++pr) {
    float puA[16], puB[16];
    const int pA = pr * 2, pB = pr * 2 + 1;
#pragma unroll
    for (int u = 0; u < 16; ++u) { puA[u] = 0.0f; puB[u] = 0.0f; }
#pragma unroll
    for (int j = 0; j < 8; ++j) {
      const int f = (j < 4) ? (l16 * 4 + j) : (64 + l16 * 4 + (j - 4));
      const float4 w0 = *(const float4*)&Wg[f * V_DIM + 0];
      const float4 w1 = *(const float4*)&Wg[f * V_DIM + 4];
      const float4 w2 = *(const float4*)&Wg[f * V_DIM + 8];
      const float4 w3 = *(const float4*)&Wg[f * V_DIM + 12];
      const float fA = acc[pA][j], fB = acc[pB][j];
      puA[0] += fA * w0.x; puA[1] += fA * w0.y; puA[2] += fA * w0.z; puA[3] += fA * w0.w;
      puA[4] += fA * w1.x; puA[5] += fA * w1.y; puA[6] += fA * w1.z; puA[7] += fA * w1.w;
      puA[8] += fA * w2.x; puA[9] += fA * w2.y; puA[10] += fA * w2.z; puA[11] += fA * w2.w;
      puA[12] += fA * w3.x; puA[13] += fA * w3.y; puA[14] += fA * w3.z; puA[15] += fA * w3.w;
      puB[0] += fB * w0.x; puB[1] += fB * w0.y; puB[2] += fB * w0.z; puB[3] += fB * w0.w;
      puB[4] += fB * w1.x; puB[5] += fB * w1.y; puB[6] += fB * w1.z; puB[7] += fB * w1.w;
      puB[8] += fB * w2.x; puB[9] += fB * w2.y; puB[10] += fB * w2.z; puB[11] += fB * w2.w;
      puB[12] += fB * w3.x; puB[13] += fB * w3.y; puB[14] += fB * w3.z; puB[15] += fB * w3.w;
    }
    gate_i[pA] = silu_f(reduce_scatter16(puA, l16) + bgv);
    gate_i[pB] = silu_f(reduce_scatter16(puB, l16) + bgv);
  }

  // ---- P3b: vm in-place in VU (channel u = l16)
#pragma unroll
  for (int i = 0; i < 4; ++i) {
    const int e = ew0 + g * 4 + i;
    const int b = VU_O + e * 48 + l16 * 3;
    const float gt = gate_i[i];
    const float vm0 = L[b + 0] * gt;
    const float vm1 = L[b + 1] * gt;
    const float vm2 = L[b + 2] * gt;
    float ss = sum16(vm0 * vm0 + vm1 * vm1 + vm2 * vm2);
    const float sc = INV_Z * rsqrtf(ss * (1.0f / 16.0f) + GVP_EPS);
    L[b + 0] = vm0 * sc;
    L[b + 1] = vm1 * sc;
    L[b + 2] = vm2 * sc;
  }

  // ---- P3c: scalar message -> SM overlay (ZF[e][0..127]; z consumed)
  {
    const float4 lgA = *(const float4*)&lng[l16 * 4];
    const float4 lgB = *(const float4*)&lng[64 + l16 * 4];
    const float4 lbA = *(const float4*)&lnb[l16 * 4];
    const float4 lbB = *(const float4*)&lnb[64 + l16 * 4];
#pragma unroll
    for (int i = 0; i < 4; ++i) {
      float s1 = 0.0f, s2 = 0.0f;
#pragma unroll
      for (int j = 0; j < 8; ++j) { s1 += acc[i][j]; s2 += acc[i][j] * acc[i][j]; }
      s1 = sum16(s1); s2 = sum16(s2);
      const float mu = s1 * (1.0f / 128.0f);
      const float var = s2 * (1.0f / 128.0f) - mu * mu;
      const float inv = rsqrtf(var + LN_EPS);
      const int e = ew0 + g * 4 + i;
      float4 o0, o1;
      o0.x = ((acc[i][0] - mu) * inv * lgA.x + lbA.x) * INV_Z;
      o0.y = ((acc[i][1] - mu) * inv * lgA.y + lbA.y) * INV_Z;
      o0.z = ((acc[i][2] - mu) * inv * lgA.z + lbA.z) * INV_Z;
      o0.w = ((acc[i][3] - mu) * inv * lgA.w + lbA.w) * INV_Z;
      o1.x = ((acc[i][4] - mu) * inv * lgB.x + lbB.x) * INV_Z;
      o1.y = ((acc[i][5] - mu) * inv * lgB.y + lbB.y) * INV_Z;
      o1.z = ((acc[i][6] - mu) * inv * lgB.z + lbB.z) * INV_Z;
      o1.w = ((acc[i][7] - mu) * inv * lgB.w + lbB.w) * INV_Z;
      *(float4*)&L[ZF_O + e * ZSTR + l16 * 4] = o0;
      *(float4*)&L[ZF_O + e * ZSTR + 64 + l16 * 4] = o1;
    }
  }
  lds_fence();

  // ---- P4: per-wave run aggregation over 16 edges; lane sweeps cols {ln, 64+ln, vu ln<48}
  int r = 0;
  while (r < 16) {
    const int d = dtile[ew0 + r];
    int rend = r + 1;
    while (rend < 16 && dtile[ew0 + rend] == d) ++rend;
    float a0 = 0.0f, a1 = 0.0f, a2 = 0.0f;
    for (int i = r; i < rend; ++i) {
      a0 += L[ZF_O + (ew0 + i) * ZSTR + ln];
      a1 += L[ZF_O + (ew0 + i) * ZSTR + 64 + ln];
      if (ln < 48) a2 += L[VU_O + (ew0 + i) * 48 + ln];
    }
    atomicAdd(&smsg[(size_t)d * S_DIM + ln], a0);
    atomicAdd(&smsg[(size_t)d * S_DIM + 64 + ln], a1);
    if (ln < 48) atomicAdd(&vmsg[(size_t)d * 48 + ln], a2);
    r = rend;
  }
}

// ---------------------------------------------------------------- node update
__global__ __launch_bounds__(256) void node_update_kernel(
    float* __restrict__ s, float* __restrict__ v,
    const float* __restrict__ smsg, const float* __restrict__ vmsg,
    const float* __restrict__ Wh, const float* __restrict__ Wu,
    const float* __restrict__ Ws, const float* __restrict__ bs,
    const float* __restrict__ Wg, const float* __restrict__ bg,
    const float* __restrict__ lng, const float* __restrict__ lnb,
    const float* __restrict__ og, const float* __restrict__ ob) {
  const int wv = threadIdx.x >> 6, lane = threadIdx.x & 63;
  const int n = blockIdx.x * 4 + wv;

  __shared__ float z[4][146];
  __shared__ float vel[4][48];
  __shared__ float vhl[4][48];
  __shared__ float fe[4][128];
  __shared__ float ga[4][16];

  float s0 = s[n * S_DIM + lane] + smsg[n * S_DIM + lane];
  float s1 = s[n * S_DIM + 64 + lane] + smsg[n * S_DIM + 64 + lane];
  float sm_ = wave_sum(s0 + s1), sq_ = wave_sum(s0 * s0 + s1 * s1);
  float mu = sm_ * (1.0f / 128.0f), var = sq_ * (1.0f / 128.0f) - mu * mu;
  float inv = rsqrtf(var + LN_EPS);
  float sa0 = (s0 - mu) * inv * og[lane] + ob[lane];
  float sa1 = (s1 - mu) * inv * og[64 + lane] + ob[64 + lane];
  z[wv][lane] = sa0; z[wv][64 + lane] = sa1;
  float vvr = 0.0f;
  if (lane < 48) vvr = v[n * 48 + lane] + vmsg[n * 48 + lane];
  float n2 = wave_sum(vvr * vvr);
  float rms = sqrtf(n2 * (1.0f / 16.0f) + GVP_EPS);
  float vln = vvr / rms;
  if (lane < 48) vel[wv][lane] = vln;
  __syncthreads();

  if (lane < 48) {
    int h = lane / 3, c = lane - 3 * h;
    float a = 0.0f;
#pragma unroll
    for (int vv = 0; vv < V_DIM; ++vv) a += vel[wv][vv * 3 + c] * Wh[vv * V_DIM + h];
    vhl[wv][lane] = a;
  }
  __syncthreads();

  if (lane < V_DIM) {
    float a = vhl[wv][lane * 3], b_ = vhl[wv][lane * 3 + 1], c_ = vhl[wv][lane * 3 + 2];
    z[wv][128 + lane] = sqrtf(a * a + b_ * b_ + c_ * c_ + GVP_EPS);
  }
  float vur = 0.0f;
  if (lane < 48) {
    int u = lane / 3, c = lane - 3 * u;
#pragma unroll
    for (int h = 0; h < V_DIM; ++h) vur += vhl[wv][h * 3 + c] * Wu[h * V_DIM + u];
  }
  __syncthreads();

  float f0 = bs[lane], f1 = bs[64 + lane];
#pragma unroll 4
  for (int k = 0; k < 144; ++k) {
    float zz = z[wv][k];
    f0 += zz * Ws[k * S_DIM + lane];
    f1 += zz * Ws[k * S_DIM + 64 + lane];
  }
  f0 = silu_f(f0); f1 = silu_f(f1);
  fe[wv][lane] = f0; fe[wv][64 + lane] = f1;
  __syncthreads();

  {
    int u = lane >> 2, q = lane & 3;
    float p = 0.0f;
#pragma unroll 8
    for (int k = q * 32; k < q * 32 + 32; ++k) p += fe[wv][k] * Wg[k * V_DIM + u];
    p += __shfl_xor(p, 1, 64);
    p += __shfl_xor(p, 2, 64);
    if (q == 0) ga[wv][u] = silu_f(p + bg[u]);
  }
  float sm2 = wave_sum(f0 + f1), sq2 = wave_sum(f0 * f0 + f1 * f1);
  float mu2 = sm2 * (1.0f / 128.0f), var2 = sq2 * (1.0f / 128.0f) - mu2 * mu2;
  float inv2 = rsqrtf(var2 + LN_EPS);
  float t0 = sa0 + (f0 - mu2) * inv2 * lng[lane] + lnb[lane];
  float t1 = sa1 + (f1 - mu2) * inv2 * lng[64 + lane] + lnb[64 + lane];
  float sm3 = wave_sum(t0 + t1), sq3 = wave_sum(t0 * t0 + t1 * t1);
  float mu3 = sm3 * (1.0f / 128.0f), var3 = sq3 * (1.0f / 128.0f) - mu3 * mu3;
  float inv3 = rsqrtf(var3 + LN_EPS);
  s[n * S_DIM + lane] = (t0 - mu3) * inv3 * og[lane] + ob[lane];
  s[n * S_DIM + 64 + lane] = (t1 - mu3) * inv3 * og[64 + lane] + ob[64 + lane];
  __syncthreads();

  float vo = 0.0f;
  if (lane < 48) { int u = lane / 3; vo = vur * ga[wv][u]; }
  float n22 = wave_sum(vo * vo);
  float rms2 = sqrtf(n22 * (1.0f / 16.0f) + GVP_EPS);
  float vr = vo / rms2;
  float v2 = (lane < 48) ? (vln + vr) : 0.0f;
  float n23 = wave_sum(v2 * v2);
  float rms3 = sqrtf(n23 * (1.0f / 16.0f) + GVP_EPS);
  if (lane < 48) v[n * 48 + lane] = v2 / rms3;
}

// ---------------------------------------------------------------- launch
extern "C" void kernel_launch(void* const* d_in, const int* in_sizes, int n_in,
                              void* d_out, int out_size, void* d_ws, size_t ws_size,
                              hipStream_t stream) {
  const float* node_h = (const float*)d_in[0];
  const float* coords = (const float*)d_in[1];
  const int* esrc = (const int*)d_in[2];
  const int* edst = (const int*)d_in[3];
  const float* emb_W1 = (const float*)d_in[4];
  const float* emb_b1 = (const float*)d_in[5];
  const float* emb_W2 = (const float*)d_in[6];
  const float* emb_b2 = (const float*)d_in[7];
  const float* norm_g = (const float*)d_in[8];
  const float* norm_b = (const float*)d_in[9];
  const float* em_Wh = (const float*)d_in[10];
  const float* em_Wu = (const float*)d_in[11];
  const float* em_Ws = (const float*)d_in[12];
  const float* em_bs = (const float*)d_in[13];
  const float* em_Wg = (const float*)d_in[14];
  const float* em_bg = (const float*)d_in[15];
  const float* em_lng = (const float*)d_in[16];
  const float* em_lnb = (const float*)d_in[17];
  const float* nu_Wh = (const float*)d_in[18];
  const float* nu_Wu = (const float*)d_in[19];
  const float* nu_Ws = (const float*)d_in[20];
  const float* nu_bs = (const float*)d_in[21];
  const float* nu_Wg = (const float*)d_in[22];
  const float* nu_bg = (const float*)d_in[23];
  const float* nu_lng = (const float*)d_in[24];
  const float* nu_lnb = (const float*)d_in[25];
  const float* ln_g = (const float*)d_in[26];
  const float* ln_b = (const float*)d_in[27];

  float* s = (float*)d_out;                      // [N,128] output 0
  float* v = s + (size_t)N_NODES * S_DIM;        // [N,16,3] output 1

  float* smsg = (float*)d_ws;                    // [N,128]
  float* vmsg = smsg + (size_t)N_NODES * S_DIM;  // [N,48]
  int* rowptr = (int*)(vmsg + (size_t)N_NODES * 48);  // [N+1] (+pad)
  int* srcs = rowptr + N_NODES + 8;              // [E]
  int* dsts = srcs + N_EDGES;                    // [E]
  int* cnt = (int*)smsg;                         // alias (setup phase only)
  int* cursor = cnt + N_NODES;                   // alias (setup phase only)

  // Scratch needed for the sorted path: msg buffers + rowptr + srcs + dsts.
  const size_t need_sorted =
      (size_t)N_NODES * 176 * sizeof(float) +
      (size_t)(N_NODES + 1 + 8) * sizeof(int) +
      (size_t)2 * N_EDGES * sizeof(int);
  // ws_size is fixed across calls -> branch is deterministic (graph-safe).
  const bool use_sorted = ws_size >= need_sorted;

  if (use_sorted) {
    // ---- dst-sort setup (edge list is a launch input; recomputed every call)
    hipMemsetAsync(cnt, 0, N_NODES * sizeof(int), stream);
    hist_kernel<<<(N_EDGES + 255) / 256, 256, 0, stream>>>(edst, cnt);
    scan_kernel<<<1, 1024, 0, stream>>>(cnt, rowptr);
    initcur_kernel<<<(N_NODES + 255) / 256, 256, 0, stream>>>(rowptr, cursor);
    scatter_kernel<<<(N_EDGES + 255) / 256, 256, 0, stream>>>(esrc, edst, cursor, srcs, dsts);
  }
  const int* esrc_use = use_sorted ? srcs : esrc;
  const int* edst_use = use_sorted ? dsts : edst;

  embed_kernel<<<N_NODES, 128, 0, stream>>>(node_h, emb_W1, emb_b1, emb_W2, emb_b2,
                                            norm_g, norm_b, s, v);
  for (int i = 0; i < 3; ++i) {
    hipMemsetAsync(smsg, 0, (size_t)N_NODES * 176 * sizeof(float), stream);
    edge_gemm_kernel<<<N_EDGES / TE, 256, 0, stream>>>(
        s, v, coords, esrc_use, edst_use, smsg, vmsg,
        em_Wh + i * H_DIM * H_DIM, em_Wu + i * H_DIM * V_DIM,
        em_Ws + i * 145 * S_DIM, em_bs + i * S_DIM,
        em_Wg + i * S_DIM * V_DIM, em_bg + i * V_DIM,
        em_lng + i * S_DIM, em_lnb + i * S_DIM);
    node_update_kernel<<<N_NODES / 4, 256, 0, stream>>>(
        s, v, smsg, vmsg,
        nu_Wh + i * V_DIM * V_DIM, nu_Wu + i * V_DIM * V_DIM,
        nu_Ws + i * 144 * S_DIM, nu_bs + i * S_DIM,
        nu_Wg + i * S_DIM * V_DIM, nu_bg + i * V_DIM,
        nu_lng + i * S_DIM, nu_lnb + i * S_DIM,
        ln_g + i * S_DIM, ln_b + i * S_DIM);
  }
}

// Round 11
// 3413.243 us; speedup vs baseline: 1.7662x; 1.1411x over previous
//
#include <hip/hip_runtime.h>
#include <math.h>

#define N_NODES 25000
#define N_EDGES 800000
#define IN_SZ 64
#define S_DIM 128
#define V_DIM 16
#define H_DIM 17
#define GVP_EPS 1e-8f
#define LN_EPS 1e-5f
#define INV_Z 0.1f
#define TE 64  // edges per block (16 per wave for edge-local phases)

// ---- LDS layout (float offsets) ----
// ZF [64][148] per-edge row: P1 scratch ve[3][20]@0, vh[3][20]@64, sh@128..144;
//   then z (s cols 0..127; sh stays at 128..144); after GEMM: feats overlay 0..127,
//   then scalar-message overlay (in-place affine).
// VU [64][48]; WhL 289; WuL 272; stile/dtile int[64] each.
#define ZF_O 0
#define ZSTR 148
#define VU_O 9472
#define WHL_O 12544
#define WUL_O 12833
#define ST_O 13105
#define DT_O 13169
#define LDS_F 13233  // 52932 B -> 3 blocks/CU

__device__ __forceinline__ float wave_sum(float x) {
#pragma unroll
  for (int off = 32; off; off >>= 1) x += __shfl_xor(x, off, 64);
  return x;
}

__device__ __forceinline__ float sum16(float x) {
#pragma unroll
  for (int off = 1; off < 16; off <<= 1) x += __shfl_xor(x, off, 64);
  return x;
}

__device__ __forceinline__ float silu_f(float x) { return x / (1.0f + __expf(-x)); }

// wave-local DS ordering fence (DS ops are in-order per wave; this pins the compiler)
__device__ __forceinline__ void lds_fence() {
  asm volatile("s_waitcnt lgkmcnt(0)" ::: "memory");
}

// reduce 16 partials across a 16-lane group; lane l16 gets total of index l16
__device__ __forceinline__ float reduce_scatter16(const float pu[16], int l16) {
  float r8[8];
#pragma unroll
  for (int u = 0; u < 8; ++u) {
    const float keep = (l16 & 8) ? pu[u + 8] : pu[u];
    const float send = (l16 & 8) ? pu[u] : pu[u + 8];
    r8[u] = keep + __shfl_xor(send, 8, 64);
  }
  float r4[4];
#pragma unroll
  for (int u = 0; u < 4; ++u) {
    const float keep = (l16 & 4) ? r8[u + 4] : r8[u];
    const float send = (l16 & 4) ? r8[u] : r8[u + 4];
    r4[u] = keep + __shfl_xor(send, 4, 64);
  }
  float r2[2];
#pragma unroll
  for (int u = 0; u < 2; ++u) {
    const float keep = (l16 & 2) ? r4[u + 2] : r4[u];
    const float send = (l16 & 2) ? r4[u] : r4[u + 2];
    r2[u] = keep + __shfl_xor(send, 2, 64);
  }
  const float keep = (l16 & 1) ? r2[1] : r2[0];
  const float send = (l16 & 1) ? r2[0] : r2[1];
  return keep + __shfl_xor(send, 1, 64);
}

// ---------------------------------------------------------------- embed
__global__ __launch_bounds__(128) void embed_kernel(
    const float* __restrict__ node_h,
    const float* __restrict__ W1, const float* __restrict__ b1,
    const float* __restrict__ W2, const float* __restrict__ b2,
    const float* __restrict__ g, const float* __restrict__ b,
    float* __restrict__ s, float* __restrict__ v) {
  const int n = blockIdx.x, tid = threadIdx.x;
  __shared__ float hb[IN_SZ];
  __shared__ float h1[S_DIM];
  __shared__ float red[4];
  if (tid < IN_SZ) hb[tid] = node_h[n * IN_SZ + tid];
  __syncthreads();
  float acc = b1[tid];
#pragma unroll 8
  for (int k = 0; k < IN_SZ; ++k) acc += hb[k] * W1[k * S_DIM + tid];
  float x = silu_f(acc);
  h1[tid] = x;
  __syncthreads();
  float acc2 = b2[tid];
#pragma unroll 8
  for (int k = 0; k < S_DIM; ++k) acc2 += h1[k] * W2[k * S_DIM + tid];
  float y = silu_f(acc2);
  const int wv = tid >> 6, lane = tid & 63;
  float sm = wave_sum(y);
  float sq = wave_sum(y * y);
  if (lane == 0) { red[wv] = sm; red[2 + wv] = sq; }
  __syncthreads();
  float tot = red[0] + red[1], tot2 = red[2] + red[3];
  float mu = tot * (1.0f / 128.0f);
  float var = tot2 * (1.0f / 128.0f) - mu * mu;
  float inv = rsqrtf(var + LN_EPS);
  s[n * S_DIM + tid] = (y - mu) * inv * g[tid] + b[tid];
  if (tid < 48) v[n * 48 + tid] = 0.0f;
}

// ---------------------------------------------------------------- sort infra
__global__ __launch_bounds__(256) void hist_kernel(const int* __restrict__ edst,
                                                   int* __restrict__ cnt) {
  int e = blockIdx.x * 256 + threadIdx.x;
  if (e < N_EDGES) atomicAdd(&cnt[edst[e]], 1);
}

__global__ __launch_bounds__(1024) void scan_kernel(const int* __restrict__ cnt,
                                                    int* __restrict__ rowptr) {
  __shared__ int wsum[16];
  __shared__ int carry_s;
  const int t = threadIdx.x, w = t >> 6, ln = t & 63;
  if (t == 0) carry_s = 0;
  __syncthreads();
  for (int base = 0; base < N_NODES; base += 1024) {
    const int idx = base + t;
    const int x = (idx < N_NODES) ? cnt[idx] : 0;
    int incl = x;
#pragma unroll
    for (int off = 1; off < 64; off <<= 1) {
      const int y = __shfl_up(incl, off, 64);
      if (ln >= off) incl += y;
    }
    if (ln == 63) wsum[w] = incl;
    __syncthreads();
    int woff = 0;
    for (int k = 0; k < w; ++k) woff += wsum[k];
    const int carry = carry_s;
    if (idx < N_NODES) rowptr[idx] = carry + woff + incl - x;
    __syncthreads();
    if (t == 1023) carry_s = carry + woff + incl;
    __syncthreads();
  }
  if (threadIdx.x == 0) rowptr[N_NODES] = carry_s;
}

__global__ __launch_bounds__(256) void initcur_kernel(const int* __restrict__ rowptr,
                                                      int* __restrict__ cursor) {
  int i = blockIdx.x * 256 + threadIdx.x;
  if (i < N_NODES) cursor[i] = rowptr[i];
}

__global__ __launch_bounds__(256) void scatter_kernel(const int* __restrict__ esrc,
                                                      const int* __restrict__ edst,
                                                      int* __restrict__ cursor,
                                                      int* __restrict__ srcs,
                                                      int* __restrict__ dsts) {
  int e = blockIdx.x * 256 + threadIdx.x;
  if (e < N_EDGES) {
    const int d = edst[e];
    const int p = atomicAdd(&cursor[d], 1);
    srcs[p] = esrc[e];
    dsts[p] = d;
  }
}

// ---------------------------------------------------------------- edge kernel
// P1/z-stage/per-edge phases: wave-local (16 edges each).
// Feats GEMM: block-cooperative COLUMN-SPLIT — wave wv computes cols
// [wv*32, wv*32+32) for all 64 edges; per-wave Ws slice = 18.5 KB (L1-resident).
// GEMM lane tile: el = ln>>2 owns edge-set {el, el+16, el+32, el+48};
//                 cg = ln&3 owns 8 consecutive cols wv*32 + cg*8 .. +7.
__global__ __launch_bounds__(256, 3) void edge_gemm_kernel(
    const float* __restrict__ s, const float* __restrict__ v,
    const float* __restrict__ coords,
    const int* __restrict__ srcs, const int* __restrict__ dsts,
    float* __restrict__ smsg, float* __restrict__ vmsg,
    const float* __restrict__ Wh, const float* __restrict__ Wu,
    const float* __restrict__ Ws, const float* __restrict__ bs,
    const float* __restrict__ Wg, const float* __restrict__ bg,
    const float* __restrict__ lng, const float* __restrict__ lnb) {
  __shared__ float L[LDS_F];
  const int t = threadIdx.x;
  const int wv = t >> 6, ln = t & 63;
  const int g = ln >> 4, l16 = ln & 15;  // per-edge phase tile
  const int el = ln >> 2, cg = ln & 3;   // GEMM tile
  const int e0 = blockIdx.x * TE;
  int* stile = (int*)&L[ST_O];
  int* dtile = (int*)&L[DT_O];
  if (t < TE) { stile[t] = srcs[e0 + t]; dtile[t] = dsts[e0 + t]; }
  for (int k = t; k < H_DIM * H_DIM; k += 256) L[WHL_O + k] = Wh[k];
  for (int k = t; k < H_DIM * V_DIM; k += 256) L[WUL_O + k] = Wu[k];
  __syncthreads();  // barrier #1

  const int ew0 = wv * 16;          // wave's first block-local edge
  const int lc = ln % 3, lq = ln / 3;

  // ---- P1a: gather ve (transposed [c][20]) into ZF[e][0..59]   (wave-local)
  for (int i = 0; i < 16; ++i) {
    const int e = ew0 + i, src = stile[e];
    if (ln < 48) {
      L[ZF_O + e * ZSTR + lc * 20 + lq + 1] = v[(size_t)src * 48 + ln];
    } else if (ln < 51) {
      const int c = ln - 48;
      L[ZF_O + e * ZSTR + c * 20] = coords[src * 3 + c] - coords[dtile[e] * 3 + c];
    }
  }
  lds_fence();

  // ---- P1b: vh (into ZF[e][64..123])
  {
    float wh[H_DIM];
    if (ln < 51) {
#pragma unroll
      for (int vv = 0; vv < H_DIM; ++vv) wh[vv] = L[WHL_O + vv * H_DIM + lq];
    }
    for (int i = 0; i < 16; ++i) {
      const int e = ew0 + i;
      if (ln < 51) {
        const int b = ZF_O + e * ZSTR + lc * 20;
        const float4 v0 = *(const float4*)&L[b + 0];
        const float4 v1 = *(const float4*)&L[b + 4];
        const float4 v2 = *(const float4*)&L[b + 8];
        const float4 v3 = *(const float4*)&L[b + 12];
        const float vl = L[b + 16];
        float a = wh[0] * v0.x + wh[1] * v0.y + wh[2] * v0.z + wh[3] * v0.w
                + wh[4] * v1.x + wh[5] * v1.y + wh[6] * v1.z + wh[7] * v1.w
                + wh[8] * v2.x + wh[9] * v2.y + wh[10] * v2.z + wh[11] * v2.w
                + wh[12] * v3.x + wh[13] * v3.y + wh[14] * v3.z + wh[15] * v3.w
                + wh[16] * vl;
        L[ZF_O + e * ZSTR + 64 + lc * 20 + lq] = a;
      }
    }
  }
  lds_fence();

  // ---- P1c: sh -> ZF[e][128..144]
  for (int i = 0; i < 16; ++i) {
    const int e = ew0 + i;
    if (ln < H_DIM) {
      const float x0 = L[ZF_O + e * ZSTR + 64 + 0 + ln];
      const float x1 = L[ZF_O + e * ZSTR + 64 + 20 + ln];
      const float x2 = L[ZF_O + e * ZSTR + 64 + 40 + ln];
      L[ZF_O + e * ZSTR + 128 + ln] = sqrtf(x0 * x0 + x1 * x1 + x2 * x2 + GVP_EPS);
    }
  }
  // ---- P1d: vu -> VU[e][u*3+c]  (reads vh; outputs disjoint from P1c)
  {
    float wu[H_DIM];
    if (ln < 48) {
#pragma unroll
      for (int h = 0; h < H_DIM; ++h) wu[h] = L[WUL_O + h * V_DIM + lq];
    }
    for (int i = 0; i < 16; ++i) {
      const int e = ew0 + i;
      if (ln < 48) {
        const int b = ZF_O + e * ZSTR + 64 + lc * 20;
        const float4 v0 = *(const float4*)&L[b + 0];
        const float4 v1 = *(const float4*)&L[b + 4];
        const float4 v2 = *(const float4*)&L[b + 8];
        const float4 v3 = *(const float4*)&L[b + 12];
        const float vl = L[b + 16];
        float a = wu[0] * v0.x + wu[1] * v0.y + wu[2] * v0.z + wu[3] * v0.w
                + wu[4] * v1.x + wu[5] * v1.y + wu[6] * v1.z + wu[7] * v1.w
                + wu[8] * v2.x + wu[9] * v2.y + wu[10] * v2.z + wu[11] * v2.w
                + wu[12] * v3.x + wu[13] * v3.y + wu[14] * v3.z + wu[15] * v3.w
                + wu[16] * vl;
        L[VU_O + e * 48 + lq * 3 + lc] = a;
      }
    }
  }
  lds_fence();

  // ---- Z stage: s[src] -> ZF[e][0..127] (overwrites dead ve/vh; sh stays)
  {
    const int le = ln >> 2, q = ln & 3;
    const int e = ew0 + le;
    const float* sp = &s[(size_t)stile[e] * S_DIM + q * 32];
    float* zp = &L[ZF_O + e * ZSTR + q * 32];
#pragma unroll
    for (int b = 0; b < 8; ++b)
      *(float4*)(zp + b * 4) = *(const float4*)(sp + b * 4);
  }
  __syncthreads();  // barrier #2: z + sh ready for ALL 64 edges

  // ---- P2: feats GEMM, column-split. acc[i][j]: edge el+i*16, col c0+j.
  const int c0 = wv * 32 + cg * 8;  // 8 consecutive cols
  float acc[4][8];
  {
    const float4 b0 = *(const float4*)&bs[c0];
    const float4 b1 = *(const float4*)&bs[c0 + 4];
#pragma unroll
    for (int i = 0; i < 4; ++i) {
      acc[i][0] = b0.x; acc[i][1] = b0.y; acc[i][2] = b0.z; acc[i][3] = b0.w;
      acc[i][4] = b1.x; acc[i][5] = b1.y; acc[i][6] = b1.z; acc[i][7] = b1.w;
    }
  }
  for (int kq = 0; kq < 36; ++kq) {
    float4 z4[4];
#pragma unroll
    for (int i = 0; i < 4; ++i)
      z4[i] = *(const float4*)&L[ZF_O + (el + i * 16) * ZSTR + kq * 4];
#pragma unroll
    for (int j = 0; j < 4; ++j) {
      const float* wrow = Ws + (size_t)(kq * 4 + j) * S_DIM;
      const float4 w0 = *(const float4*)(wrow + c0);
      const float4 w1 = *(const float4*)(wrow + c0 + 4);
#pragma unroll
      for (int i = 0; i < 4; ++i) {
        const float z = (j == 0) ? z4[i].x : (j == 1) ? z4[i].y : (j == 2) ? z4[i].z : z4[i].w;
        acc[i][0] += z * w0.x; acc[i][1] += z * w0.y;
        acc[i][2] += z * w0.z; acc[i][3] += z * w0.w;
        acc[i][4] += z * w1.x; acc[i][5] += z * w1.y;
        acc[i][6] += z * w1.z; acc[i][7] += z * w1.w;
      }
    }
  }
  {  // k = 144 tail (z = sh[16] at ZF[e][144])
    const float* wrow = Ws + (size_t)144 * S_DIM;
    const float4 w0 = *(const float4*)(wrow + c0);
    const float4 w1 = *(const float4*)(wrow + c0 + 4);
#pragma unroll
    for (int i = 0; i < 4; ++i) {
      const float z = L[ZF_O + (el + i * 16) * ZSTR + 144];
      acc[i][0] += z * w0.x; acc[i][1] += z * w0.y;
      acc[i][2] += z * w0.z; acc[i][3] += z * w0.w;
      acc[i][4] += z * w1.x; acc[i][5] += z * w1.y;
      acc[i][6] += z * w1.z; acc[i][7] += z * w1.w;
    }
  }
  // silu in regs
#pragma unroll
  for (int i = 0; i < 4; ++i)
#pragma unroll
    for (int j = 0; j < 8; ++j) acc[i][j] = silu_f(acc[i][j]);
  __syncthreads();  // barrier #3: everyone done READING z

  // ---- feats write: acc -> ZF[e][c0..c0+7] (overwrites z)
#pragma unroll
  for (int i = 0; i < 4; ++i) {
    const int e = el + i * 16;
    float4 o0, o1;
    o0.x = acc[i][0]; o0.y = acc[i][1]; o0.z = acc[i][2]; o0.w = acc[i][3];
    o1.x = acc[i][4]; o1.y = acc[i][5]; o1.z = acc[i][6]; o1.w = acc[i][7];
    *(float4*)&L[ZF_O + e * ZSTR + c0] = o0;
    *(float4*)&L[ZF_O + e * ZSTR + c0 + 4] = o1;
  }
  __syncthreads();  // barrier #4: full feats rows ready

  // ---- per-edge phases, wave-local on edges ew0..ew0+15 (f from LDS)
  // lane tile: group g owns edges ew0+g*4..+3; cols {l16*4..+3, 64+l16*4..+3}
  float f[4][8];
#pragma unroll
  for (int i = 0; i < 4; ++i) {
    const int e = ew0 + g * 4 + i;
    const float4 a = *(const float4*)&L[ZF_O + e * ZSTR + l16 * 4];
    const float4 b = *(const float4*)&L[ZF_O + e * ZSTR + 64 + l16 * 4];
    f[i][0] = a.x; f[i][1] = a.y; f[i][2] = a.z; f[i][3] = a.w;
    f[i][4] = b.x; f[i][5] = b.y; f[i][6] = b.z; f[i][7] = b.w;
  }
  lds_fence();

  // ---- P3a: gate (Wg from global, L1-resident)
  const float bgv = bg[l16];
  float gate_i[4];
#pragma unroll
  for (int pr = 0; pr < 2; ++pr) {
    float puA[16], puB[16];
    const int pA = pr * 2, pB = pr * 2 + 1;
#pragma unroll
    for (int u = 0; u < 16; ++u) { puA[u] = 0.0f; puB[u] = 0.0f; }
#pragma unroll
    for (int j = 0; j < 8; ++j) {
      const int fc = (j < 4) ? (l16 * 4 + j) : (64 + l16 * 4 + (j - 4));
      const float4 w0 = *(const float4*)&Wg[fc * V_DIM + 0];
      const float4 w1 = *(const float4*)&Wg[fc * V_DIM + 4];
      const float4 w2 = *(const float4*)&Wg[fc * V_DIM + 8];
      const float4 w3 = *(const float4*)&Wg[fc * V_DIM + 12];
      const float fA = f[pA][j], fB = f[pB][j];
      puA[0] += fA * w0.x; puA[1] += fA * w0.y; puA[2] += fA * w0.z; puA[3] += fA * w0.w;
      puA[4] += fA * w1.x; puA[5] += fA * w1.y; puA[6] += fA * w1.z; puA[7] += fA * w1.w;
      puA[8] += fA * w2.x; puA[9] += fA * w2.y; puA[10] += fA * w2.z; puA[11] += fA * w2.w;
      puA[12] += fA * w3.x; puA[13] += fA * w3.y; puA[14] += fA * w3.z; puA[15] += fA * w3.w;
      puB[0] += fB * w0.x; puB[1] += fB * w0.y; puB[2] += fB * w0.z; puB[3] += fB * w0.w;
      puB[4] += fB * w1.x; puB[5] += fB * w1.y; puB[6] += fB * w1.z; puB[7] += fB * w1.w;
      puB[8] += fB * w2.x; puB[9] += fB * w2.y; puB[10] += fB * w2.z; puB[11] += fB * w2.w;
      puB[12] += fB * w3.x; puB[13] += fB * w3.y; puB[14] += fB * w3.z; puB[15] += fB * w3.w;
    }
    gate_i[pA] = silu_f(reduce_scatter16(puA, l16) + bgv);
    gate_i[pB] = silu_f(reduce_scatter16(puB, l16) + bgv);
  }

  // ---- P3b: vm in-place in VU (channel u = l16)
#pragma unroll
  for (int i = 0; i < 4; ++i) {
    const int e = ew0 + g * 4 + i;
    const int b = VU_O + e * 48 + l16 * 3;
    const float gt = gate_i[i];
    const float vm0 = L[b + 0] * gt;
    const float vm1 = L[b + 1] * gt;
    const float vm2 = L[b + 2] * gt;
    float ss = sum16(vm0 * vm0 + vm1 * vm1 + vm2 * vm2);
    const float sc = INV_Z * rsqrtf(ss * (1.0f / 16.0f) + GVP_EPS);
    L[b + 0] = vm0 * sc;
    L[b + 1] = vm1 * sc;
    L[b + 2] = vm2 * sc;
  }

  // ---- P3c: scalar message in-place over feats (wave-owned rows)
  {
    const float4 lgA = *(const float4*)&lng[l16 * 4];
    const float4 lgB = *(const float4*)&lng[64 + l16 * 4];
    const float4 lbA = *(const float4*)&lnb[l16 * 4];
    const float4 lbB = *(const float4*)&lnb[64 + l16 * 4];
#pragma unroll
    for (int i = 0; i < 4; ++i) {
      float s1 = 0.0f, s2 = 0.0f;
#pragma unroll
      for (int j = 0; j < 8; ++j) { s1 += f[i][j]; s2 += f[i][j] * f[i][j]; }
      s1 = sum16(s1); s2 = sum16(s2);
      const float mu = s1 * (1.0f / 128.0f);
      const float var = s2 * (1.0f / 128.0f) - mu * mu;
      const float inv = rsqrtf(var + LN_EPS);
      const int e = ew0 + g * 4 + i;
      float4 o0, o1;
      o0.x = ((f[i][0] - mu) * inv * lgA.x + lbA.x) * INV_Z;
      o0.y = ((f[i][1] - mu) * inv * lgA.y + lbA.y) * INV_Z;
      o0.z = ((f[i][2] - mu) * inv * lgA.z + lbA.z) * INV_Z;
      o0.w = ((f[i][3] - mu) * inv * lgA.w + lbA.w) * INV_Z;
      o1.x = ((f[i][4] - mu) * inv * lgB.x + lbB.x) * INV_Z;
      o1.y = ((f[i][5] - mu) * inv * lgB.y + lbB.y) * INV_Z;
      o1.z = ((f[i][6] - mu) * inv * lgB.z + lbB.z) * INV_Z;
      o1.w = ((f[i][7] - mu) * inv * lgB.w + lbB.w) * INV_Z;
      *(float4*)&L[ZF_O + e * ZSTR + l16 * 4] = o0;
      *(float4*)&L[ZF_O + e * ZSTR + 64 + l16 * 4] = o1;
    }
  }
  lds_fence();

  // ---- P4: per-wave run aggregation over 16 edges
  int r = 0;
  while (r < 16) {
    const int d = dtile[ew0 + r];
    int rend = r + 1;
    while (rend < 16 && dtile[ew0 + rend] == d) ++rend;
    float a0 = 0.0f, a1 = 0.0f, a2 = 0.0f;
    for (int i = r; i < rend; ++i) {
      a0 += L[ZF_O + (ew0 + i) * ZSTR + ln];
      a1 += L[ZF_O + (ew0 + i) * ZSTR + 64 + ln];
      if (ln < 48) a2 += L[VU_O + (ew0 + i) * 48 + ln];
    }
    atomicAdd(&smsg[(size_t)d * S_DIM + ln], a0);
    atomicAdd(&smsg[(size_t)d * S_DIM + 64 + ln], a1);
    if (ln < 48) atomicAdd(&vmsg[(size_t)d * 48 + ln], a2);
    r = rend;
  }
}

// ---------------------------------------------------------------- node update
__global__ __launch_bounds__(256) void node_update_kernel(
    float* __restrict__ s, float* __restrict__ v,
    const float* __restrict__ smsg, const float* __restrict__ vmsg,
    const float* __restrict__ Wh, const float* __restrict__ Wu,
    const float* __restrict__ Ws, const float* __restrict__ bs,
    const float* __restrict__ Wg, const float* __restrict__ bg,
    const float* __restrict__ lng, const float* __restrict__ lnb,
    const float* __restrict__ og, const float* __restrict__ ob) {
  const int wv = threadIdx.x >> 6, lane = threadIdx.x & 63;
  const int n = blockIdx.x * 4 + wv;

  __shared__ float z[4][146];
  __shared__ float vel[4][48];
  __shared__ float vhl[4][48];
  __shared__ float fe[4][128];
  __shared__ float ga[4][16];

  float s0 = s[n * S_DIM + lane] + smsg[n * S_DIM + lane];
  float s1 = s[n * S_DIM + 64 + lane] + smsg[n * S_DIM + 64 + lane];
  float sm_ = wave_sum(s0 + s1), sq_ = wave_sum(s0 * s0 + s1 * s1);
  float mu = sm_ * (1.0f / 128.0f), var = sq_ * (1.0f / 128.0f) - mu * mu;
  float inv = rsqrtf(var + LN_EPS);
  float sa0 = (s0 - mu) * inv * og[lane] + ob[lane];
  float sa1 = (s1 - mu) * inv * og[64 + lane] + ob[64 + lane];
  z[wv][lane] = sa0; z[wv][64 + lane] = sa1;
  float vvr = 0.0f;
  if (lane < 48) vvr = v[n * 48 + lane] + vmsg[n * 48 + lane];
  float n2 = wave_sum(vvr * vvr);
  float rms = sqrtf(n2 * (1.0f / 16.0f) + GVP_EPS);
  float vln = vvr / rms;
  if (lane < 48) vel[wv][lane] = vln;
  __syncthreads();

  if (lane < 48) {
    int h = lane / 3, c = lane - 3 * h;
    float a = 0.0f;
#pragma unroll
    for (int vv = 0; vv < V_DIM; ++vv) a += vel[wv][vv * 3 + c] * Wh[vv * V_DIM + h];
    vhl[wv][lane] = a;
  }
  __syncthreads();

  if (lane < V_DIM) {
    float a = vhl[wv][lane * 3], b_ = vhl[wv][lane * 3 + 1], c_ = vhl[wv][lane * 3 + 2];
    z[wv][128 + lane] = sqrtf(a * a + b_ * b_ + c_ * c_ + GVP_EPS);
  }
  float vur = 0.0f;
  if (lane < 48) {
    int u = lane / 3, c = lane - 3 * u;
#pragma unroll
    for (int h = 0; h < V_DIM; ++h) vur += vhl[wv][h * 3 + c] * Wu[h * V_DIM + u];
  }
  __syncthreads();

  float f0 = bs[lane], f1 = bs[64 + lane];
#pragma unroll 4
  for (int k = 0; k < 144; ++k) {
    float zz = z[wv][k];
    f0 += zz * Ws[k * S_DIM + lane];
    f1 += zz * Ws[k * S_DIM + 64 + lane];
  }
  f0 = silu_f(f0); f1 = silu_f(f1);
  fe[wv][lane] = f0; fe[wv][64 + lane] = f1;
  __syncthreads();

  {
    int u = lane >> 2, q = lane & 3;
    float p = 0.0f;
#pragma unroll 8
    for (int k = q * 32; k < q * 32 + 32; ++k) p += fe[wv][k] * Wg[k * V_DIM + u];
    p += __shfl_xor(p, 1, 64);
    p += __shfl_xor(p, 2, 64);
    if (q == 0) ga[wv][u] = silu_f(p + bg[u]);
  }
  float sm2 = wave_sum(f0 + f1), sq2 = wave_sum(f0 * f0 + f1 * f1);
  float mu2 = sm2 * (1.0f / 128.0f), var2 = sq2 * (1.0f / 128.0f) - mu2 * mu2;
  float inv2 = rsqrtf(var2 + LN_EPS);
  float t0 = sa0 + (f0 - mu2) * inv2 * lng[lane] + lnb[lane];
  float t1 = sa1 + (f1 - mu2) * inv2 * lng[64 + lane] + lnb[64 + lane];
  float sm3 = wave_sum(t0 + t1), sq3 = wave_sum(t0 * t0 + t1 * t1);
  float mu3 = sm3 * (1.0f / 128.0f), var3 = sq3 * (1.0f / 128.0f) - mu3 * mu3;
  float inv3 = rsqrtf(var3 + LN_EPS);
  s[n * S_DIM + lane] = (t0 - mu3) * inv3 * og[lane] + ob[lane];
  s[n * S_DIM + 64 + lane] = (t1 - mu3) * inv3 * og[64 + lane] + ob[64 + lane];
  __syncthreads();

  float vo = 0.0f;
  if (lane < 48) { int u = lane / 3; vo = vur * ga[wv][u]; }
  float n22 = wave_sum(vo * vo);
  float rms2 = sqrtf(n22 * (1.0f / 16.0f) + GVP_EPS);
  float vr = vo / rms2;
  float v2 = (lane < 48) ? (vln + vr) : 0.0f;
  float n23 = wave_sum(v2 * v2);
  float rms3 = sqrtf(n23 * (1.0f / 16.0f) + GVP_EPS);
  if (lane < 48) v[n * 48 + lane] = v2 / rms3;
}

// ---------------------------------------------------------------- launch
extern "C" void kernel_launch(void* const* d_in, const int* in_sizes, int n_in,
                              void* d_out, int out_size, void* d_ws, size_t ws_size,
                              hipStream_t stream) {
  const float* node_h = (const float*)d_in[0];
  const float* coords = (const float*)d_in[1];
  const int* esrc = (const int*)d_in[2];
  const int* edst = (const int*)d_in[3];
  const float* emb_W1 = (const float*)d_in[4];
  const float* emb_b1 = (const float*)d_in[5];
  const float* emb_W2 = (const float*)d_in[6];
  const float* emb_b2 = (const float*)d_in[7];
  const float* norm_g = (const float*)d_in[8];
  const float* norm_b = (const float*)d_in[9];
  const float* em_Wh = (const float*)d_in[10];
  const float* em_Wu = (const float*)d_in[11];
  const float* em_Ws = (const float*)d_in[12];
  const float* em_bs = (const float*)d_in[13];
  const float* em_Wg = (const float*)d_in[14];
  const float* em_bg = (const float*)d_in[15];
  const float* em_lng = (const float*)d_in[16];
  const float* em_lnb = (const float*)d_in[17];
  const float* nu_Wh = (const float*)d_in[18];
  const float* nu_Wu = (const float*)d_in[19];
  const float* nu_Ws = (const float*)d_in[20];
  const float* nu_bs = (const float*)d_in[21];
  const float* nu_Wg = (const float*)d_in[22];
  const float* nu_bg = (const float*)d_in[23];
  const float* nu_lng = (const float*)d_in[24];
  const float* nu_lnb = (const float*)d_in[25];
  const float* ln_g = (const float*)d_in[26];
  const float* ln_b = (const float*)d_in[27];

  float* s = (float*)d_out;                      // [N,128] output 0
  float* v = s + (size_t)N_NODES * S_DIM;        // [N,16,3] output 1

  float* smsg = (float*)d_ws;                    // [N,128]
  float* vmsg = smsg + (size_t)N_NODES * S_DIM;  // [N,48]
  int* rowptr = (int*)(vmsg + (size_t)N_NODES * 48);  // [N+1] (+pad)
  int* srcs = rowptr + N_NODES + 8;              // [E]
  int* dsts = srcs + N_EDGES;                    // [E]
  int* cnt = (int*)smsg;                         // alias (setup phase only)
  int* cursor = cnt + N_NODES;                   // alias (setup phase only)

  // Scratch needed for the sorted path: msg buffers + rowptr + srcs + dsts.
  const size_t need_sorted =
      (size_t)N_NODES * 176 * sizeof(float) +
      (size_t)(N_NODES + 1 + 8) * sizeof(int) +
      (size_t)2 * N_EDGES * sizeof(int);
  // ws_size is fixed across calls -> branch is deterministic (graph-safe).
  const bool use_sorted = ws_size >= need_sorted;

  if (use_sorted) {
    // ---- dst-sort setup (edge list is a launch input; recomputed every call)
    hipMemsetAsync(cnt, 0, N_NODES * sizeof(int), stream);
    hist_kernel<<<(N_EDGES + 255) / 256, 256, 0, stream>>>(edst, cnt);
    scan_kernel<<<1, 1024, 0, stream>>>(cnt, rowptr);
    initcur_kernel<<<(N_NODES + 255) / 256, 256, 0, stream>>>(rowptr, cursor);
    scatter_kernel<<<(N_EDGES + 255) / 256, 256, 0, stream>>>(esrc, edst, cursor, srcs, dsts);
  }
  const int* esrc_use = use_sorted ? srcs : esrc;
  const int* edst_use = use_sorted ? dsts : edst;

  embed_kernel<<<N_NODES, 128, 0, stream>>>(node_h, emb_W1, emb_b1, emb_W2, emb_b2,
                                            norm_g, norm_b, s, v);
  for (int i = 0; i < 3; ++i) {
    hipMemsetAsync(smsg, 0, (size_t)N_NODES * 176 * sizeof(float), stream);
    edge_gemm_kernel<<<N_EDGES / TE, 256, 0, stream>>>(
        s, v, coords, esrc_use, edst_use, smsg, vmsg,
        em_Wh + i * H_DIM * H_DIM, em_Wu + i * H_DIM * V_DIM,
        em_Ws + i * 145 * S_DIM, em_bs + i * S_DIM,
        em_Wg + i * S_DIM * V_DIM, em_bg + i * V_DIM,
        em_lng + i * S_DIM, em_lnb + i * S_DIM);
    node_update_kernel<<<N_NODES / 4, 256, 0, stream>>>(
        s, v, smsg, vmsg,
        nu_Wh + i * V_DIM * V_DIM, nu_Wu + i * V_DIM * V_DIM,
        nu_Ws + i * 144 * S_DIM, nu_bs + i * S_DIM,
        nu_Wg + i * S_DIM * V_DIM, nu_bg + i * V_DIM,
        nu_lng + i * S_DIM, nu_lnb + i * S_DIM,
        ln_g + i * S_DIM, ln_b + i * S_DIM);
  }
}